// Round 8
// baseline (334.930 us; speedup 1.0000x reference)
//
#include <hip/hip_runtime.h>
#include <stdint.h>

#define S_LEN 2048
#define D_DIM 7168
#define H_NUM 64
#define HD_DIM 128
#define QLR_DIM 1536
#define NQ_DIM 8192      // H*HD
#define ROPE_DIM 64
#define HALF_DIM 32
#define TOPK_N 512
#define NEG_INF_F (-1e30f)
#define LN_EPS 1e-6f
#define W_SCALE 0.011048543456039806f   // 1/sqrt(64*128)

#define KCHUNKS 7
#define KCHUNK_SZ 1024
#define NKT 24                           // QLR/64 K-tiles for qgemm

// Q fragment layout: Qfrag[h][sgrp][ks][lane] of short8 (16B chunks).
#define QF_HSTRIDE (128 * 4 * 64 * 8)   // elements per head = 262144

// workspace layout (float offsets)
#define QBF_OFF 0                                    // S*NQ bf16 = 8388608 floats
#define ALORA_OFF (QBF_OFF + S_LEN * NQ_DIM / 2)     // q_lora bf16
#define WT_OFF   (ALORA_OFF + S_LEN * QLR_DIM / 2)   // wq_b^T bf16
#define XBF_OFF  (WT_OFF + NQ_DIM * QLR_DIM / 2)     // x bf16: S*D/2 floats
#define WT2_OFF  (XBF_OFF + S_LEN * D_DIM / 2)       // [wk|wproj]^T bf16: 192*D/2
#define KF_OFF   (WT2_OFF + 192 * D_DIM / 2)         // (unused now)
#define KBF_OFF  (KF_OFF + S_LEN * HD_DIM)
#define WF_OFF   (KBF_OFF + S_LEN * HD_DIM / 2)
#define SC_OFF   (WF_OFF + S_LEN * H_NUM)            // scores S*S fp32
// split-K partials (7*S*192 = 2.75M floats) alias the score region (4.19M)

// prep kernel block ranges
#define PREP_CAST_QL 1536                 // q_lora cast blocks
#define PREP_CAST_X  7168                 // x cast blocks
#define PREP_CAST_BLKS (PREP_CAST_QL + PREP_CAST_X)
#define PREP_WQB_BLKS 3072
#define PREP_WKP_BLKS 336
#define PREP_TOTAL (PREP_CAST_BLKS + PREP_WQB_BLKS + PREP_WKP_BLKS)

typedef __attribute__((ext_vector_type(8))) short short8;
typedef __attribute__((ext_vector_type(4))) float floatx4;

__device__ __forceinline__ ushort f2bf(float f) {
    unsigned int u = __float_as_uint(f);
    u += 0x7FFFu + ((u >> 16) & 1u);   // round-to-nearest-even
    return (ushort)(u >> 16);
}
__device__ __forceinline__ unsigned int pack2bf(float lo, float hi) {
    return (unsigned int)f2bf(lo) | ((unsigned int)f2bf(hi) << 16);
}

__device__ __forceinline__ void gld_lds16(const ushort* g, ushort* l) {
    __builtin_amdgcn_global_load_lds(
        (const __attribute__((address_space(1))) unsigned int*)g,
        (__attribute__((address_space(3))) unsigned int*)l, 16, 0, 0);
}

// ---------------------------------------------------------------------------
// Kernel 0: fused prep — bf16 casts (q_lora, x) + weight transposes
// (wq_b -> WT, [wk|wproj] -> WT2).  One launch, block-range dispatch.
// ---------------------------------------------------------------------------
__global__ __launch_bounds__(256) void prep_kernel(
    const float* __restrict__ q_lora, ushort* __restrict__ Albf,
    const float* __restrict__ x, ushort* __restrict__ Xbf,
    const float* __restrict__ W, ushort* __restrict__ WT,
    const float* __restrict__ WK, const float* __restrict__ WP,
    ushort* __restrict__ WT2)
{
    __shared__ ushort tl[64][72];
    const int b = blockIdx.x;
    const int t = threadIdx.x;

    if (b < PREP_CAST_BLKS) {
        const float* in; ushort* out; int lb;
        if (b < PREP_CAST_QL) { in = q_lora; out = Albf; lb = b; }
        else                  { in = x;      out = Xbf;  lb = b - PREP_CAST_QL; }
        int g = (lb * 256 + t) * 8;
        float4 a = *(const float4*)&in[g];
        float4 c = *(const float4*)&in[g + 4];
        uint4 v;
        v.x = pack2bf(a.x, a.y); v.y = pack2bf(a.z, a.w);
        v.z = pack2bf(c.x, c.y); v.w = pack2bf(c.z, c.w);
        *(uint4*)&out[g] = v;
        return;
    }

    const int bid = b - PREP_CAST_BLKS;
    const int r = t >> 4, c4 = (t & 15) * 4;

    if (bid < PREP_WQB_BLKS) {
        const int n0 = (bid & 127) * 64, k0 = (bid >> 7) * 64;
#pragma unroll
        for (int u = 0; u < 4; u++) {
            int kk = r + u * 16;
            float4 v = *(const float4*)&W[(size_t)(k0 + kk) * NQ_DIM + n0 + c4];
            tl[c4 + 0][kk] = f2bf(v.x);
            tl[c4 + 1][kk] = f2bf(v.y);
            tl[c4 + 2][kk] = f2bf(v.z);
            tl[c4 + 3][kk] = f2bf(v.w);
        }
        __syncthreads();
#pragma unroll
        for (int u = 0; u < 2; u++) {
            int i = t + u * 256;             // 512 chunks of 16B
            int nr = i >> 3, c8 = (i & 7) * 8;
            uint4 v = *(const uint4*)&tl[nr][c8];
            *(uint4*)&WT[(size_t)(n0 + nr) * QLR_DIM + k0 + c8] = v;
        }
    } else {
        const int rem = bid - PREP_WQB_BLKS;
        const int ntile = rem % 3;
        const int k0 = (rem / 3) * 64;
        const float* src; int ld, cbase;
        if (ntile < 2) { src = WK; ld = HD_DIM; cbase = ntile * 64; }
        else           { src = WP; ld = H_NUM; cbase = 0; }
#pragma unroll
        for (int u = 0; u < 4; u++) {
            int kk = r + u * 16;
            float4 v = *(const float4*)&src[(size_t)(k0 + kk) * ld + cbase + c4];
            tl[c4 + 0][kk] = f2bf(v.x);
            tl[c4 + 1][kk] = f2bf(v.y);
            tl[c4 + 2][kk] = f2bf(v.z);
            tl[c4 + 3][kk] = f2bf(v.w);
        }
        __syncthreads();
#pragma unroll
        for (int u = 0; u < 2; u++) {
            int i = t + u * 256;
            int nr = i >> 3, c8 = (i & 7) * 8;
            uint4 v = *(const uint4*)&tl[nr][c8];
            *(uint4*)&WT2[(size_t)(ntile * 64 + nr) * D_DIM + k0 + c8] = v;
        }
    }
}

// ---------------------------------------------------------------------------
// Kernel 1: Q = q_lora @ wq_b.  256x256 tile, BK=64, 8 waves, 4 phases/tile
// (best counter-measured variant this session: 63.7-65.6 us, MfmaUtil ~31).
// B-fragments register-resident across the K-tile (reads 8/8/4/4 = 24);
// staging for tile k+1 at ph1/ph2; single vmcnt(0) fence per tile.
// NOTE (measured): counted-vmcnt variants (R3) and single-barrier (R5) both
// regress to ~89 us — phase barriers pin the staging issue ~3000 cyc before
// its drain; without them the compiler sinks the loads and the drain eats
// full HBM latency.  Do not re-attempt without .s-level verification.
// ---------------------------------------------------------------------------
__global__ __launch_bounds__(512, 2) void qgemm_mfma_kernel(
    const ushort* __restrict__ Abf,   // bf16 [S][QLR]
    const ushort* __restrict__ WT,    // bf16 [NQ][QLR]
    const float* __restrict__ cosp, const float* __restrict__ sinp,
    ushort* __restrict__ Qo)          // bf16 frag layout
{
    __shared__ __align__(16) ushort lds[65536];   // 128 KiB: A[2][256][64] | B[2][256][64]

    const int tid = threadIdx.x;
    const int lane = tid & 63;
    const int wave = tid >> 6;
    const int m = lane & 15;
    const int q = lane >> 4;
    const int wm = wave & 1;          // M half (128 rows)
    const int wn = wave >> 1;         // N quarter (64 cols)

    const int wg = blockIdx.x;
    const int xcd = wg & 7, lid = wg >> 3;      // lid in [0,32)
    const int bx = xcd * 4 + (lid & 3);         // [0,32)  N-block
    const int by = lid >> 2;                    // [0,8)   M-block
    const int m0 = by * 256;
    const int n0 = bx * 256;

    const ushort* sgA[2][2];
    const ushort* sgB[2][2];
    unsigned int ldoff[2][2];
#pragma unroll
    for (int h = 0; h < 2; h++)
#pragma unroll
        for (int r = 0; r < 2; r++) {
            int s = r * 512 + wave * 64 + lane;
            int row = s >> 3, c = s & 7;
            int kg = c ^ (row & 7);
            sgA[h][r] = Abf + (size_t)(m0 + h * 128 + row) * QLR_DIM + kg * 8;
            sgB[h][r] = WT  + (size_t)(n0 + h * 128 + row) * QLR_DIM + kg * 8;
            ldoff[h][r] = (unsigned int)(h * 8192 + (r * 512 + wave * 64) * 8);
        }

    auto stageA = [&](int kt, int h) {
        ushort* dbase = &lds[(kt & 1) * 16384];
        gld_lds16(sgA[h][0] + kt * 64, dbase + ldoff[h][0]);
        gld_lds16(sgA[h][1] + kt * 64, dbase + ldoff[h][1]);
    };
    auto stageB = [&](int kt, int h) {
        ushort* dbase = &lds[32768 + (kt & 1) * 16384];
        gld_lds16(sgB[h][0] + kt * 64, dbase + ldoff[h][0]);
        gld_lds16(sgB[h][1] + kt * 64, dbase + ldoff[h][1]);
    };

    unsigned int aoff[2], boff[2];
#pragma unroll
    for (int ks = 0; ks < 2; ks++) {
        unsigned int xr = (unsigned int)(((((ks << 2) + q) ^ (m & 7))) * 8);
        aoff[ks] = (unsigned int)((wm * 128 + m) * 64) + xr;
        boff[ks] = (unsigned int)((wn * 64 + m) * 64) + xr;
    }

    floatx4 acc[8][4];
#pragma unroll
    for (int i = 0; i < 8; i++)
#pragma unroll
        for (int j = 0; j < 4; j++) acc[i][j] = (floatx4){0.f, 0.f, 0.f, 0.f};

    // prologue: tile 0 staged fully, drained (depth-1 pipeline thereafter)
    stageA(0, 0); stageA(0, 1); stageB(0, 0); stageB(0, 1);
    asm volatile("s_waitcnt vmcnt(0)" ::: "memory");
    __builtin_amdgcn_s_barrier();

#pragma unroll 2
    for (int kt = 0; kt < NKT; ++kt) {
        const ushort* as = &lds[(kt & 1) * 16384];
        const ushort* bs = &lds[32768 + (kt & 1) * 16384];
        const bool pf = (kt + 1 < NKT);

        short8 af[4], bf0[4], bf1[4];

        // -------- phase 1: M-half0 x ks0  (reads 8, stages A + B0) ---------
#pragma unroll
        for (int mt = 0; mt < 4; mt++)
            af[mt] = *(const short8*)&as[aoff[0] + mt * 1024];
#pragma unroll
        for (int nt = 0; nt < 4; nt++)
            bf0[nt] = *(const short8*)&bs[boff[0] + nt * 1024];
        if (pf) { stageA(kt + 1, 0); stageA(kt + 1, 1); stageB(kt + 1, 0); }
        __builtin_amdgcn_s_barrier();
        __builtin_amdgcn_s_setprio(1);
#pragma unroll
        for (int mt = 0; mt < 4; mt++)
#pragma unroll
            for (int nt = 0; nt < 4; nt++)
                acc[mt][nt] = __builtin_amdgcn_mfma_f32_16x16x32_bf16(
                    af[mt], bf0[nt], acc[mt][nt], 0, 0, 0);
        __builtin_amdgcn_s_setprio(0);
        __builtin_amdgcn_s_barrier();

        // -------- phase 2: M-half0 x ks1  (reads 8, stages B1) -------------
#pragma unroll
        for (int mt = 0; mt < 4; mt++)
            af[mt] = *(const short8*)&as[aoff[1] + mt * 1024];
#pragma unroll
        for (int nt = 0; nt < 4; nt++)
            bf1[nt] = *(const short8*)&bs[boff[1] + nt * 1024];
        if (pf) stageB(kt + 1, 1);
        __builtin_amdgcn_s_barrier();
        __builtin_amdgcn_s_setprio(1);
#pragma unroll
        for (int mt = 0; mt < 4; mt++)
#pragma unroll
            for (int nt = 0; nt < 4; nt++)
                acc[mt][nt] = __builtin_amdgcn_mfma_f32_16x16x32_bf16(
                    af[mt], bf1[nt], acc[mt][nt], 0, 0, 0);
        __builtin_amdgcn_s_setprio(0);
        __builtin_amdgcn_s_barrier();

        // -------- phase 3: M-half1 x ks0  (reads 4, reuses bf0) ------------
#pragma unroll
        for (int mt = 0; mt < 4; mt++)
            af[mt] = *(const short8*)&as[aoff[0] + 4096 + mt * 1024];
        __builtin_amdgcn_s_barrier();
        __builtin_amdgcn_s_setprio(1);
#pragma unroll
        for (int mt = 0; mt < 4; mt++)
#pragma unroll
            for (int nt = 0; nt < 4; nt++)
                acc[4 + mt][nt] = __builtin_amdgcn_mfma_f32_16x16x32_bf16(
                    af[mt], bf0[nt], acc[4 + mt][nt], 0, 0, 0);
        __builtin_amdgcn_s_setprio(0);
        __builtin_amdgcn_s_barrier();

        // -------- phase 4: M-half1 x ks1  (reads 4, reuses bf1) ------------
#pragma unroll
        for (int mt = 0; mt < 4; mt++)
            af[mt] = *(const short8*)&as[aoff[1] + 4096 + mt * 1024];
        __builtin_amdgcn_s_barrier();
        __builtin_amdgcn_s_setprio(1);
#pragma unroll
        for (int mt = 0; mt < 4; mt++)
#pragma unroll
            for (int nt = 0; nt < 4; nt++)
                acc[4 + mt][nt] = __builtin_amdgcn_mfma_f32_16x16x32_bf16(
                    af[mt], bf1[nt], acc[4 + mt][nt], 0, 0, 0);
        __builtin_amdgcn_s_setprio(0);
        asm volatile("s_waitcnt vmcnt(0)" ::: "memory");
        __builtin_amdgcn_s_barrier();
    }

    // ---- epilogue: RoPE + bf16 + fragment-layout store, one head at a time
    __syncthreads();
    ushort* ep = lds;                 // [256][pitch 136] bf16
    const int h0 = bx * 2;
    const int sgrp0 = m0 >> 4;

#pragma unroll
    for (int hh = 0; hh < 2; hh++) {
        if ((wn >> 1) == hh) {
            const int dbase = (wn & 1) * 64;
            const bool do_rope = ((wn & 1) == 0);
#pragma unroll
            for (int ai = 0; ai < 8; ai++) {
                const int srow0 = m0 + wm * 128 + (ai & 3) * 16 + (ai >> 2) * 64 + q * 4;
                const int lrow0 = srow0 - m0;
#pragma unroll
                for (int bj = 0; bj < 4; bj++) {
                    const int d = dbase + bj * 16 + m;
                    float o[4];
                    if (do_rope) {
                        const int jj = d >> 1;
#pragma unroll
                        for (int r = 0; r < 4; r++) {
                            float x = acc[(ai >> 2) * 4 + (ai & 3)][bj][r];
                            float p = __shfl_xor(x, 1, 64);
                            float c = cosp[(srow0 + r) * HALF_DIM + jj];
                            float sn = sinp[(srow0 + r) * HALF_DIM + jj];
                            o[r] = (d & 1) ? (p * sn + x * c) : (x * c - p * sn);
                        }
                    } else {
#pragma unroll
                        for (int r = 0; r < 4; r++)
                            o[r] = acc[(ai >> 2) * 4 + (ai & 3)][bj][r];
                    }
#pragma unroll
                    for (int r = 0; r < 4; r++)
                        ep[(lrow0 + r) * 136 + d] = f2bf(o[r]);
                }
            }
        }
        __syncthreads();
        const size_t hstr = (size_t)(h0 + hh) * QF_HSTRIDE;
#pragma unroll
        for (int u = 0; u < 8; u++) {
            int i = u * 512 + tid;            // 4096 chunks of 16B
            int sgl = i >> 8, c = i & 255;
            int ks = c >> 6, ln = c & 63;
            int srow = sgl * 16 + (ln & 15);
            int d0 = (ks << 5) + ((ln >> 4) << 3);
            uint4 v = *(const uint4*)&ep[srow * 136 + d0];
            *(uint4*)&Qo[hstr + ((((size_t)(sgrp0 + sgl) * 4 + ks) * 64 + ln) * 8)] = v;
        }
        __syncthreads();
    }
}

// ---------------------------------------------------------------------------
// Kernel 2: [ktmp|w] = x @ [wk|wproj] via bf16 MFMA, split-K. grid (16,3,7).
// Ported to the PROVEN qgemm rhythm: double-buffered LDS, 2 phases per
// K-step {reads(k) + early stage-issue(k+1) -> s_barrier (pins loads) ->
// MFMA}, full drain only at step end (__syncthreads).  Hazard: stage(k+1)
// targets the buffer last read in step k-1, whose readers all passed the
// step-(k-1) end barrier.
// ---------------------------------------------------------------------------
__global__ __launch_bounds__(256) void kw_mfma_kernel(
    const ushort* __restrict__ Xbf,   // bf16 [S][D]
    const ushort* __restrict__ WT2,   // bf16 [192][D]
    float* __restrict__ partial)      // [kc][S][192]
{
    __shared__ ushort As[2 * 128 * 64];   // 32 KB
    __shared__ ushort Bs[2 * 64 * 64];    // 16 KB

    const int tid = threadIdx.x;
    const int lane = tid & 63;
    const int wave = tid >> 6;
    const int m = lane & 15;
    const int q = lane >> 4;
    const int wm = wave & 1, wn = wave >> 1;
    const int m0 = blockIdx.x * 128;
    const int n0 = blockIdx.y * 64;
    const int kc = blockIdx.z;
    const size_t kbase = (size_t)kc * KCHUNK_SZ;

    const ushort* agp[4];
    unsigned int abase[4];
#pragma unroll
    for (int u = 0; u < 4; u++) {
        int s = (u * 4 + wave) * 64 + lane;
        int row = s >> 3, c = s & 7;
        int kg = c ^ (row & 7);
        agp[u] = Xbf + (size_t)(m0 + row) * D_DIM + kbase + kg * 8;
        abase[u] = (unsigned int)((u * 4 + wave) * 64 * 8);
    }
    const ushort* bgp[2];
    unsigned int bbase[2];
#pragma unroll
    for (int u = 0; u < 2; u++) {
        int s = (u * 4 + wave) * 64 + lane;
        int row = s >> 3, c = s & 7;
        int kg = c ^ (row & 7);
        bgp[u] = WT2 + (size_t)(n0 + row) * D_DIM + kbase + kg * 8;
        bbase[u] = (unsigned int)((u * 4 + wave) * 64 * 8);
    }

    auto stage = [&](int t) {
        ushort* da = &As[(t & 1) * 8192];
        ushort* db = &Bs[(t & 1) * 4096];
#pragma unroll
        for (int u = 0; u < 4; u++) gld_lds16(agp[u] + t * 64, da + abase[u]);
#pragma unroll
        for (int u = 0; u < 2; u++) gld_lds16(bgp[u] + t * 64, db + bbase[u]);
    };

    floatx4 acc[4][2];
#pragma unroll
    for (int i = 0; i < 4; i++)
#pragma unroll
        for (int j = 0; j < 2; j++) acc[i][j] = (floatx4){0.f, 0.f, 0.f, 0.f};

    stage(0);
    __syncthreads();

#pragma unroll 2
    for (int t = 0; t < KCHUNK_SZ / 64; ++t) {
        const ushort* as = &As[(t & 1) * 8192];
        const ushort* bs = &Bs[(t & 1) * 4096];

        short8 af[4], bfr[2];

        // ---- phase 1: ks0  (reads 6; stage(t+1) issued early) ----
#pragma unroll
        for (int mt = 0; mt < 4; mt++) {
            int row = wm * 64 + mt * 16 + m;
            af[mt] = *(const short8*)&as[row * 64 + ((q ^ (m & 7)) * 8)];
        }
#pragma unroll
        for (int nt = 0; nt < 2; nt++) {
            int row = wn * 32 + nt * 16 + m;
            bfr[nt] = *(const short8*)&bs[row * 64 + ((q ^ (m & 7)) * 8)];
        }
        if (t + 1 < KCHUNK_SZ / 64) stage(t + 1);
        __builtin_amdgcn_s_barrier();
        __builtin_amdgcn_s_setprio(1);
#pragma unroll
        for (int mt = 0; mt < 4; mt++)
#pragma unroll
            for (int nt = 0; nt < 2; nt++)
                acc[mt][nt] = __builtin_amdgcn_mfma_f32_16x16x32_bf16(
                    af[mt], bfr[nt], acc[mt][nt], 0, 0, 0);
        __builtin_amdgcn_s_setprio(0);
        __builtin_amdgcn_s_barrier();

        // ---- phase 2: ks1  (reads 6) ----
#pragma unroll
        for (int mt = 0; mt < 4; mt++) {
            int row = wm * 64 + mt * 16 + m;
            af[mt] = *(const short8*)&as[row * 64 + (((4 + q) ^ (m & 7)) * 8)];
        }
#pragma unroll
        for (int nt = 0; nt < 2; nt++) {
            int row = wn * 32 + nt * 16 + m;
            bfr[nt] = *(const short8*)&bs[row * 64 + (((4 + q) ^ (m & 7)) * 8)];
        }
        __builtin_amdgcn_s_barrier();
        __builtin_amdgcn_s_setprio(1);
#pragma unroll
        for (int mt = 0; mt < 4; mt++)
#pragma unroll
            for (int nt = 0; nt < 2; nt++)
                acc[mt][nt] = __builtin_amdgcn_mfma_f32_16x16x32_bf16(
                    af[mt], bfr[nt], acc[mt][nt], 0, 0, 0);
        __builtin_amdgcn_s_setprio(0);
        __syncthreads();   // drains vmcnt (stage t+1 landed) + lgkm; fences reuse
    }

#pragma unroll
    for (int mt = 0; mt < 4; mt++) {
        int grow = m0 + wm * 64 + mt * 16 + q * 4;
#pragma unroll
        for (int nt = 0; nt < 2; nt++) {
            int gn = n0 + wn * 32 + nt * 16 + m;
#pragma unroll
            for (int r = 0; r < 4; r++)
                partial[((size_t)kc * S_LEN + grow + r) * 192 + gn] = acc[mt][nt][r];
        }
    }
}

// ---------------------------------------------------------------------------
// Kernel 3: fused split-K reduce + layernorm + RoPE.  One block per s-row,
// 192 threads (3 waves): t<128 -> K path (LN+rope -> Kbf), t>=128 -> W path.
// ---------------------------------------------------------------------------
__global__ __launch_bounds__(192) void kw_reduce_norm_kernel(
    const float* __restrict__ partial,
    const float* __restrict__ gw, const float* __restrict__ gb,
    const float* __restrict__ cosp, const float* __restrict__ sinp,
    ushort* __restrict__ Kbf, float* __restrict__ Wo)
{
    __shared__ float red[128];
    __shared__ float sh[128];
    const int m = blockIdx.x, t = threadIdx.x;

    float s = 0.f;
#pragma unroll
    for (int c = 0; c < KCHUNKS; c++)
        s += partial[((size_t)c * S_LEN + m) * 192 + t];

    if (t >= HD_DIM)
        Wo[(size_t)m * H_NUM + (t - HD_DIM)] = s * W_SCALE;

    if (t < HD_DIM) red[t] = s;
    __syncthreads();
    for (int off = 64; off > 0; off >>= 1) {
        if (t < off) red[t] += red[t + off];
        __syncthreads();
    }
    float mu = red[0] * (1.f / HD_DIM);
    __syncthreads();
    float dv = s - mu;
    if (t < HD_DIM) red[t] = dv * dv;
    __syncthreads();
    for (int off = 64; off > 0; off >>= 1) {
        if (t < off) red[t] += red[t + off];
        __syncthreads();
    }
    float var = red[0] * (1.f / HD_DIM);
    float rs = rsqrtf(var + LN_EPS);
    float kn = 0.f;
    if (t < HD_DIM) { kn = dv * rs * gw[t] + gb[t]; sh[t] = kn; }
    __syncthreads();
    if (t < HD_DIM) {
        float out;
        if (t < ROPE_DIM) {
            int jj = t >> 1;
            float c = cosp[m * HALF_DIM + jj], sn = sinp[m * HALF_DIM + jj];
            out = ((t & 1) == 0) ? (sh[t] * c - sh[t + 1] * sn)
                                 : (sh[t - 1] * sn + sh[t] * c);
        } else {
            out = kn;
        }
        Kbf[(size_t)m * HD_DIM + t] = f2bf(out);
    }
}

// ---------------------------------------------------------------------------
// Kernel 4: index_score via bf16 MFMA, barrier-free head loop.
// + T5 setprio around MFMA clusters (this kernel matches the regime where it
// measured +4-7%: independent 1-barrier blocks, waves at different phases).
// ---------------------------------------------------------------------------
__global__ __launch_bounds__(256, 2) void attn_mfma_kernel(
    const ushort* __restrict__ Qb,  // bf16 frag layout [h][sgrp][ks][lane]x8
    const ushort* __restrict__ Kb,  // bf16 [S][HD]
    const float* __restrict__ Wf,   // fp32 [S][H], pre-scaled
    float* __restrict__ SC)
{
    __shared__ float Wsm[64 * 68];

    const int bidx = blockIdx.x;
    const int x = bidx & 7, j = bidx >> 3;
    const int g1 = x + 1, g2 = 32 - x, g3 = x + 9;   // group sizes (g4=24-x)
    int ts, tt;
    if (j < g1)                { ts = x;      tt = j; }
    else if (j < g1 + g2)      { ts = 31 - x; tt = j - g1; }
    else if (j < g1 + g2 + g3) { ts = x + 8;  tt = j - g1 - g2; }
    else                       { ts = 23 - x; tt = j - g1 - g2 - g3; }
    const int s0 = ts * 64, t0 = tt * 64;

    const int tid = threadIdx.x;
    const int lane = tid & 63;
    const int m = lane & 15;
    const int q = lane >> 4;
    const int strip = (tid >> 6) * 16;

    {
        const float4* gw = (const float4*)(Wf + (size_t)s0 * H_NUM);
#pragma unroll
        for (int u = 0; u < 4; u++) {
            int ch = tid + u * 256;
            float4 v = gw[ch];
            *(float4*)&Wsm[(ch >> 4) * 68 + (ch & 15) * 4] = v;
        }
    }

    short8 bf[4][4];   // [t-tile][k-step] — resident all block
#pragma unroll
    for (int tile = 0; tile < 4; tile++)
#pragma unroll
        for (int ks = 0; ks < 4; ks++)
            bf[tile][ks] = *(const short8*)
                &Kb[(size_t)(t0 + tile * 16 + m) * HD_DIM + ks * 32 + q * 8];

    __syncthreads();   // Wsm ready (only barrier)

    float acc[4][4];
#pragma unroll
    for (int tile = 0; tile < 4; tile++)
#pragma unroll
        for (int r = 0; r < 4; r++) acc[tile][r] = 0.f;

    const int sgrp = ts * 4 + (strip >> 4);
    const ushort* qfb = Qb + ((size_t)sgrp * 4 * 64 + lane) * 8;
    const float* wrow = &Wsm[(strip + q * 4) * 68];

    auto loadQ = [&](short8* dst, int h) {
        const ushort* p = qfb + (size_t)h * QF_HSTRIDE;
#pragma unroll
        for (int ks = 0; ks < 4; ks++) dst[ks] = *(const short8*)&p[ks * 512];
    };
    auto computeH = [&](const short8* af, int h) {
        float wv[4];
#pragma unroll
        for (int r = 0; r < 4; r++) wv[r] = wrow[r * 68 + h];
#pragma unroll
        for (int tile = 0; tile < 4; tile++) {
            floatx4 p = {0.f, 0.f, 0.f, 0.f};
            __builtin_amdgcn_s_setprio(1);
#pragma unroll
            for (int ks = 0; ks < 4; ks++)
                p = __builtin_amdgcn_mfma_f32_16x16x32_bf16(af[ks], bf[tile][ks], p, 0, 0, 0);
            __builtin_amdgcn_s_setprio(0);
#pragma unroll
            for (int r = 0; r < 4; r++)
                acc[tile][r] += fmaxf(p[r], 0.f) * wv[r];
        }
    };

    short8 afA[4], afB[4];
    loadQ(afA, 0);
    for (int h = 0; h < H_NUM; h += 2) {
        loadQ(afB, h + 1);
        computeH(afA, h);
        if (h + 2 < H_NUM) loadQ(afA, h + 2);
        computeH(afB, h + 1);
    }

#pragma unroll
    for (int tile = 0; tile < 4; tile++)
#pragma unroll
        for (int r = 0; r < 4; r++)
            SC[(size_t)(s0 + strip + q * 4 + r) * S_LEN + t0 + tile * 16 + m] =
                acc[tile][r];
}

// ---------------------------------------------------------------------------
// Kernel 5: per-row top-512, u32 compressed keys, causal-length-adaptive
// partial bitonic.  512 threads: halves the serial iterations per sort step
// (dominant phase-1 loop runs <=2 iters instead of <=4).
// ---------------------------------------------------------------------------
__device__ __forceinline__ unsigned int fkey(float f) {
    unsigned int u = __float_as_uint(f);
    return (u & 0x80000000u) ? ~u : (u | 0x80000000u);
}

__global__ __launch_bounds__(512) void topk_kernel(
    const float* __restrict__ SC, float* __restrict__ outv, float* __restrict__ outi)
{
    __shared__ unsigned int key[S_LEN];
    __shared__ float val[S_LEN];
    const int s = blockIdx.x, tid = threadIdx.x;
    const int nchunks = (s >> 9) + 1;          // 1..4 active 512-chunks
    const int nact = nchunks << 9;

    for (int t = tid; t < nact; t += 512) {
        float v = (t <= s) ? SC[(size_t)s * S_LEN + t] : NEG_INF_F;
        val[t] = v;
        key[t] = (fkey(v) & 0xFFFFF800u) | (unsigned int)(S_LEN - 1 - t);
    }
    __syncthreads();

    // Phase 1: sort each active 512-chunk descending (local-index network)
    for (int k2 = 2; k2 <= 512; k2 <<= 1) {
        for (int j = k2 >> 1; j > 0; j >>= 1) {
            for (int p = tid; p < (nact >> 1); p += 512) {
                int i = 2 * p - (p & (j - 1));
                int il = i & 511;
                unsigned int a = key[i], b = key[i + j];
                bool up = ((il & k2) == 0);
                bool sw = up ? (a < b) : (a > b);
                if (sw) { key[i] = b; key[i + j] = a; }
            }
            __syncthreads();
        }
    }

    // Phase 2: fold chunks c=1.. into chunk 0 (top-512 of union each time)
    for (int c = 1; c < nchunks; c++) {
        {
            int p = tid;                          // 512 threads, 512 slots
            unsigned int a = key[p], b = key[(c << 9) + 511 - p];
            key[p] = a > b ? a : b;               // bitonic, contains top-512
        }
        __syncthreads();
        for (int j = 256; j > 0; j >>= 1) {       // bitonic merge, descending
            if (tid < 256) {
                int i = 2 * tid - (tid & (j - 1));
                unsigned int a = key[i], b = key[i + j];
                if (a < b) { key[i] = b; key[i + j] = a; }
            }
            __syncthreads();
        }
    }

    for (int i2 = tid; i2 < TOPK_N; i2 += 512) {
        unsigned int kv = key[i2];
        int t = S_LEN - 1 - (int)(kv & 0x7FFu);
        outv[(size_t)s * TOPK_N + i2] = val[t];
        outi[(size_t)s * TOPK_N + i2] = (float)t;
    }
}

// ---------------------------------------------------------------------------
extern "C" void kernel_launch(void* const* d_in, const int* in_sizes, int n_in,
                              void* d_out, int out_size, void* d_ws, size_t ws_size,
                              hipStream_t stream)
{
    (void)in_sizes; (void)n_in; (void)out_size; (void)ws_size;
    const float* x      = (const float*)d_in[0];
    const float* q_lora = (const float*)d_in[1];
    const float* wq_b   = (const float*)d_in[2];
    const float* wk     = (const float*)d_in[3];
    const float* wproj  = (const float*)d_in[4];
    const float* knw    = (const float*)d_in[5];
    const float* knb    = (const float*)d_in[6];
    const float* cosp   = (const float*)d_in[7];
    const float* sinp   = (const float*)d_in[8];

    float* ws = (float*)d_ws;
    ushort* Qbf  = (ushort*)(ws + QBF_OFF);
    ushort* Albf = (ushort*)(ws + ALORA_OFF);
    ushort* WTbf = (ushort*)(ws + WT_OFF);
    ushort* Xbf  = (ushort*)(ws + XBF_OFF);
    ushort* WT2  = (ushort*)(ws + WT2_OFF);
    ushort* Kbf  = (ushort*)(ws + KBF_OFF);
    float*  Wf   = ws + WF_OFF;
    float*  SCb  = ws + SC_OFF;
    float*  partial = ws + SC_OFF;   // alias: consumed before SC is written

    float* outv = (float*)d_out;
    float* outi = outv + (size_t)S_LEN * TOPK_N;

    prep_kernel<<<PREP_TOTAL, 256, 0, stream>>>(
        q_lora, Albf, x, Xbf, wq_b, WTbf, wk, wproj, WT2);
    kw_mfma_kernel<<<dim3(S_LEN / 128, 3, KCHUNKS), 256, 0, stream>>>(Xbf, WT2, partial);
    kw_reduce_norm_kernel<<<S_LEN, 192, 0, stream>>>(
        partial, knw, knb, cosp, sinp, Kbf, Wf);
    qgemm_mfma_kernel<<<256, 512, 0, stream>>>(Albf, WTbf, cosp, sinp, Qbf);
    attn_mfma_kernel<<<528, 256, 0, stream>>>(Qbf, Kbf, Wf, SCb);
    topk_kernel<<<S_LEN, 512, 0, stream>>>(SCb, outv, outi);
}

// Round 10
// 327.994 us; speedup vs baseline: 1.0211x; 1.0211x over previous
//
#include <hip/hip_runtime.h>
#include <stdint.h>

#define S_LEN 2048
#define D_DIM 7168
#define H_NUM 64
#define HD_DIM 128
#define QLR_DIM 1536
#define NQ_DIM 8192      // H*HD
#define ROPE_DIM 64
#define HALF_DIM 32
#define TOPK_N 512
#define NEG_INF_F (-1e30f)
#define LN_EPS 1e-6f
#define W_SCALE 0.011048543456039806f   // 1/sqrt(64*128)

#define KCHUNKS 16
#define KCHUNK_SZ 448                    // 16*448 = 7168; 768 blocks = 3.0/CU
#define NKT 24                           // QLR/64 K-tiles for qgemm

// Q fragment layout: Qfrag[h][sgrp][ks][lane] of short8 (16B chunks).
#define QF_HSTRIDE (128 * 4 * 64 * 8)   // elements per head = 262144

// workspace layout (float offsets)
#define QBF_OFF 0                                    // S*NQ bf16 = 8388608 floats
#define ALORA_OFF (QBF_OFF + S_LEN * NQ_DIM / 2)     // q_lora bf16
#define WT_OFF   (ALORA_OFF + S_LEN * QLR_DIM / 2)   // wq_b^T bf16
#define XBF_OFF  (WT_OFF + NQ_DIM * QLR_DIM / 2)     // x bf16: S*D/2 floats
#define WT2_OFF  (XBF_OFF + S_LEN * D_DIM / 2)       // [wk|wproj]^T bf16: 192*D/2
#define KF_OFF   (WT2_OFF + 192 * D_DIM / 2)         // (unused now)
#define KBF_OFF  (KF_OFF + S_LEN * HD_DIM)
#define WF_OFF   (KBF_OFF + S_LEN * HD_DIM / 2)
#define SC_OFF   (WF_OFF + S_LEN * H_NUM)            // scores S*S fp32
// split-K partials (16*S*192 = 6.29M floats) alias the QBF region (8.39M):
// produced by kernel 2, consumed by kernel 3, Qbf first written by kernel 4.

// prep kernel block ranges
#define PREP_CAST_QL 1536                 // q_lora cast blocks
#define PREP_CAST_X  7168                 // x cast blocks
#define PREP_CAST_BLKS (PREP_CAST_QL + PREP_CAST_X)
#define PREP_WQB_BLKS 3072
#define PREP_WKP_BLKS 336
#define PREP_TOTAL (PREP_CAST_BLKS + PREP_WQB_BLKS + PREP_WKP_BLKS)

typedef __attribute__((ext_vector_type(8))) short short8;
typedef __attribute__((ext_vector_type(4))) float floatx4;

__device__ __forceinline__ ushort f2bf(float f) {
    unsigned int u = __float_as_uint(f);
    u += 0x7FFFu + ((u >> 16) & 1u);   // round-to-nearest-even
    return (ushort)(u >> 16);
}
__device__ __forceinline__ unsigned int pack2bf(float lo, float hi) {
    return (unsigned int)f2bf(lo) | ((unsigned int)f2bf(hi) << 16);
}

__device__ __forceinline__ void gld_lds16(const ushort* g, ushort* l) {
    __builtin_amdgcn_global_load_lds(
        (const __attribute__((address_space(1))) unsigned int*)g,
        (__attribute__((address_space(3))) unsigned int*)l, 16, 0, 0);
}

// ---------------------------------------------------------------------------
// Kernel 0: fused prep — bf16 casts (q_lora, x) + weight transposes
// (wq_b -> WT, [wk|wproj] -> WT2).  One launch, block-range dispatch.
// ---------------------------------------------------------------------------
__global__ __launch_bounds__(256) void prep_kernel(
    const float* __restrict__ q_lora, ushort* __restrict__ Albf,
    const float* __restrict__ x, ushort* __restrict__ Xbf,
    const float* __restrict__ W, ushort* __restrict__ WT,
    const float* __restrict__ WK, const float* __restrict__ WP,
    ushort* __restrict__ WT2)
{
    __shared__ ushort tl[64][72];
    const int b = blockIdx.x;
    const int t = threadIdx.x;

    if (b < PREP_CAST_BLKS) {
        const float* in; ushort* out; int lb;
        if (b < PREP_CAST_QL) { in = q_lora; out = Albf; lb = b; }
        else                  { in = x;      out = Xbf;  lb = b - PREP_CAST_QL; }
        int g = (lb * 256 + t) * 8;
        float4 a = *(const float4*)&in[g];
        float4 c = *(const float4*)&in[g + 4];
        uint4 v;
        v.x = pack2bf(a.x, a.y); v.y = pack2bf(a.z, a.w);
        v.z = pack2bf(c.x, c.y); v.w = pack2bf(c.z, c.w);
        *(uint4*)&out[g] = v;
        return;
    }

    const int bid = b - PREP_CAST_BLKS;
    const int r = t >> 4, c4 = (t & 15) * 4;

    if (bid < PREP_WQB_BLKS) {
        const int n0 = (bid & 127) * 64, k0 = (bid >> 7) * 64;
#pragma unroll
        for (int u = 0; u < 4; u++) {
            int kk = r + u * 16;
            float4 v = *(const float4*)&W[(size_t)(k0 + kk) * NQ_DIM + n0 + c4];
            tl[c4 + 0][kk] = f2bf(v.x);
            tl[c4 + 1][kk] = f2bf(v.y);
            tl[c4 + 2][kk] = f2bf(v.z);
            tl[c4 + 3][kk] = f2bf(v.w);
        }
        __syncthreads();
#pragma unroll
        for (int u = 0; u < 2; u++) {
            int i = t + u * 256;             // 512 chunks of 16B
            int nr = i >> 3, c8 = (i & 7) * 8;
            uint4 v = *(const uint4*)&tl[nr][c8];
            *(uint4*)&WT[(size_t)(n0 + nr) * QLR_DIM + k0 + c8] = v;
        }
    } else {
        const int rem = bid - PREP_WQB_BLKS;
        const int ntile = rem % 3;
        const int k0 = (rem / 3) * 64;
        const float* src; int ld, cbase;
        if (ntile < 2) { src = WK; ld = HD_DIM; cbase = ntile * 64; }
        else           { src = WP; ld = H_NUM; cbase = 0; }
#pragma unroll
        for (int u = 0; u < 4; u++) {
            int kk = r + u * 16;
            float4 v = *(const float4*)&src[(size_t)(k0 + kk) * ld + cbase + c4];
            tl[c4 + 0][kk] = f2bf(v.x);
            tl[c4 + 1][kk] = f2bf(v.y);
            tl[c4 + 2][kk] = f2bf(v.z);
            tl[c4 + 3][kk] = f2bf(v.w);
        }
        __syncthreads();
#pragma unroll
        for (int u = 0; u < 2; u++) {
            int i = t + u * 256;
            int nr = i >> 3, c8 = (i & 7) * 8;
            uint4 v = *(const uint4*)&tl[nr][c8];
            *(uint4*)&WT2[(size_t)(ntile * 64 + nr) * D_DIM + k0 + c8] = v;
        }
    }
}

// ---------------------------------------------------------------------------
// Kernel 1: Q = q_lora @ wq_b.  256x256 tile, BK=64, 8 waves, 4 phases/tile
// (best counter-measured variant this session: 63.7-66.1 us, MfmaUtil ~31).
// B-fragments register-resident across the K-tile (reads 8/8/4/4 = 24);
// staging for tile k+1 at ph1/ph2; single vmcnt(0) fence per tile.
// NOTE (measured): counted-vmcnt variants (R3) and single-barrier (R5) both
// regress to ~89 us — phase barriers pin the staging issue ~3000 cyc before
// its drain; without them the compiler sinks the loads and the drain eats
// full HBM latency.  Do not re-attempt without .s-level verification.
// ---------------------------------------------------------------------------
__global__ __launch_bounds__(512, 2) void qgemm_mfma_kernel(
    const ushort* __restrict__ Abf,   // bf16 [S][QLR]
    const ushort* __restrict__ WT,    // bf16 [NQ][QLR]
    const float* __restrict__ cosp, const float* __restrict__ sinp,
    ushort* __restrict__ Qo)          // bf16 frag layout
{
    __shared__ __align__(16) ushort lds[65536];   // 128 KiB: A[2][256][64] | B[2][256][64]

    const int tid = threadIdx.x;
    const int lane = tid & 63;
    const int wave = tid >> 6;
    const int m = lane & 15;
    const int q = lane >> 4;
    const int wm = wave & 1;          // M half (128 rows)
    const int wn = wave >> 1;         // N quarter (64 cols)

    const int wg = blockIdx.x;
    const int xcd = wg & 7, lid = wg >> 3;      // lid in [0,32)
    const int bx = xcd * 4 + (lid & 3);         // [0,32)  N-block
    const int by = lid >> 2;                    // [0,8)   M-block
    const int m0 = by * 256;
    const int n0 = bx * 256;

    const ushort* sgA[2][2];
    const ushort* sgB[2][2];
    unsigned int ldoff[2][2];
#pragma unroll
    for (int h = 0; h < 2; h++)
#pragma unroll
        for (int r = 0; r < 2; r++) {
            int s = r * 512 + wave * 64 + lane;
            int row = s >> 3, c = s & 7;
            int kg = c ^ (row & 7);
            sgA[h][r] = Abf + (size_t)(m0 + h * 128 + row) * QLR_DIM + kg * 8;
            sgB[h][r] = WT  + (size_t)(n0 + h * 128 + row) * QLR_DIM + kg * 8;
            ldoff[h][r] = (unsigned int)(h * 8192 + (r * 512 + wave * 64) * 8);
        }

    auto stageA = [&](int kt, int h) {
        ushort* dbase = &lds[(kt & 1) * 16384];
        gld_lds16(sgA[h][0] + kt * 64, dbase + ldoff[h][0]);
        gld_lds16(sgA[h][1] + kt * 64, dbase + ldoff[h][1]);
    };
    auto stageB = [&](int kt, int h) {
        ushort* dbase = &lds[32768 + (kt & 1) * 16384];
        gld_lds16(sgB[h][0] + kt * 64, dbase + ldoff[h][0]);
        gld_lds16(sgB[h][1] + kt * 64, dbase + ldoff[h][1]);
    };

    unsigned int aoff[2], boff[2];
#pragma unroll
    for (int ks = 0; ks < 2; ks++) {
        unsigned int xr = (unsigned int)(((((ks << 2) + q) ^ (m & 7))) * 8);
        aoff[ks] = (unsigned int)((wm * 128 + m) * 64) + xr;
        boff[ks] = (unsigned int)((wn * 64 + m) * 64) + xr;
    }

    floatx4 acc[8][4];
#pragma unroll
    for (int i = 0; i < 8; i++)
#pragma unroll
        for (int j = 0; j < 4; j++) acc[i][j] = (floatx4){0.f, 0.f, 0.f, 0.f};

    // prologue: tile 0 staged fully, drained (depth-1 pipeline thereafter)
    stageA(0, 0); stageA(0, 1); stageB(0, 0); stageB(0, 1);
    asm volatile("s_waitcnt vmcnt(0)" ::: "memory");
    __builtin_amdgcn_s_barrier();

#pragma unroll 2
    for (int kt = 0; kt < NKT; ++kt) {
        const ushort* as = &lds[(kt & 1) * 16384];
        const ushort* bs = &lds[32768 + (kt & 1) * 16384];
        const bool pf = (kt + 1 < NKT);

        short8 af[4], bf0[4], bf1[4];

        // -------- phase 1: M-half0 x ks0  (reads 8, stages A + B0) ---------
#pragma unroll
        for (int mt = 0; mt < 4; mt++)
            af[mt] = *(const short8*)&as[aoff[0] + mt * 1024];
#pragma unroll
        for (int nt = 0; nt < 4; nt++)
            bf0[nt] = *(const short8*)&bs[boff[0] + nt * 1024];
        if (pf) { stageA(kt + 1, 0); stageA(kt + 1, 1); stageB(kt + 1, 0); }
        __builtin_amdgcn_s_barrier();
        __builtin_amdgcn_s_setprio(1);
#pragma unroll
        for (int mt = 0; mt < 4; mt++)
#pragma unroll
            for (int nt = 0; nt < 4; nt++)
                acc[mt][nt] = __builtin_amdgcn_mfma_f32_16x16x32_bf16(
                    af[mt], bf0[nt], acc[mt][nt], 0, 0, 0);
        __builtin_amdgcn_s_setprio(0);
        __builtin_amdgcn_s_barrier();

        // -------- phase 2: M-half0 x ks1  (reads 8, stages B1) -------------
#pragma unroll
        for (int mt = 0; mt < 4; mt++)
            af[mt] = *(const short8*)&as[aoff[1] + mt * 1024];
#pragma unroll
        for (int nt = 0; nt < 4; nt++)
            bf1[nt] = *(const short8*)&bs[boff[1] + nt * 1024];
        if (pf) stageB(kt + 1, 1);
        __builtin_amdgcn_s_barrier();
        __builtin_amdgcn_s_setprio(1);
#pragma unroll
        for (int mt = 0; mt < 4; mt++)
#pragma unroll
            for (int nt = 0; nt < 4; nt++)
                acc[mt][nt] = __builtin_amdgcn_mfma_f32_16x16x32_bf16(
                    af[mt], bf1[nt], acc[mt][nt], 0, 0, 0);
        __builtin_amdgcn_s_setprio(0);
        __builtin_amdgcn_s_barrier();

        // -------- phase 3: M-half1 x ks0  (reads 4, reuses bf0) ------------
#pragma unroll
        for (int mt = 0; mt < 4; mt++)
            af[mt] = *(const short8*)&as[aoff[0] + 4096 + mt * 1024];
        __builtin_amdgcn_s_barrier();
        __builtin_amdgcn_s_setprio(1);
#pragma unroll
        for (int mt = 0; mt < 4; mt++)
#pragma unroll
            for (int nt = 0; nt < 4; nt++)
                acc[4 + mt][nt] = __builtin_amdgcn_mfma_f32_16x16x32_bf16(
                    af[mt], bf0[nt], acc[4 + mt][nt], 0, 0, 0);
        __builtin_amdgcn_s_setprio(0);
        __builtin_amdgcn_s_barrier();

        // -------- phase 4: M-half1 x ks1  (reads 4, reuses bf1) ------------
#pragma unroll
        for (int mt = 0; mt < 4; mt++)
            af[mt] = *(const short8*)&as[aoff[1] + 4096 + mt * 1024];
        __builtin_amdgcn_s_barrier();
        __builtin_amdgcn_s_setprio(1);
#pragma unroll
        for (int mt = 0; mt < 4; mt++)
#pragma unroll
            for (int nt = 0; nt < 4; nt++)
                acc[4 + mt][nt] = __builtin_amdgcn_mfma_f32_16x16x32_bf16(
                    af[mt], bf1[nt], acc[4 + mt][nt], 0, 0, 0);
        __builtin_amdgcn_s_setprio(0);
        asm volatile("s_waitcnt vmcnt(0)" ::: "memory");
        __builtin_amdgcn_s_barrier();
    }

    // ---- epilogue: RoPE + bf16 + fragment-layout store, one head at a time
    __syncthreads();
    ushort* ep = lds;                 // [256][pitch 136] bf16
    const int h0 = bx * 2;
    const int sgrp0 = m0 >> 4;

#pragma unroll
    for (int hh = 0; hh < 2; hh++) {
        if ((wn >> 1) == hh) {
            const int dbase = (wn & 1) * 64;
            const bool do_rope = ((wn & 1) == 0);
#pragma unroll
            for (int ai = 0; ai < 8; ai++) {
                const int srow0 = m0 + wm * 128 + (ai & 3) * 16 + (ai >> 2) * 64 + q * 4;
                const int lrow0 = srow0 - m0;
#pragma unroll
                for (int bj = 0; bj < 4; bj++) {
                    const int d = dbase + bj * 16 + m;
                    float o[4];
                    if (do_rope) {
                        const int jj = d >> 1;
#pragma unroll
                        for (int r = 0; r < 4; r++) {
                            float x = acc[(ai >> 2) * 4 + (ai & 3)][bj][r];
                            float p = __shfl_xor(x, 1, 64);
                            float c = cosp[(srow0 + r) * HALF_DIM + jj];
                            float sn = sinp[(srow0 + r) * HALF_DIM + jj];
                            o[r] = (d & 1) ? (p * sn + x * c) : (x * c - p * sn);
                        }
                    } else {
#pragma unroll
                        for (int r = 0; r < 4; r++)
                            o[r] = acc[(ai >> 2) * 4 + (ai & 3)][bj][r];
                    }
#pragma unroll
                    for (int r = 0; r < 4; r++)
                        ep[(lrow0 + r) * 136 + d] = f2bf(o[r]);
                }
            }
        }
        __syncthreads();
        const size_t hstr = (size_t)(h0 + hh) * QF_HSTRIDE;
#pragma unroll
        for (int u = 0; u < 8; u++) {
            int i = u * 512 + tid;            // 4096 chunks of 16B
            int sgl = i >> 8, c = i & 255;
            int ks = c >> 6, ln = c & 63;
            int srow = sgl * 16 + (ln & 15);
            int d0 = (ks << 5) + ((ln >> 4) << 3);
            uint4 v = *(const uint4*)&ep[srow * 136 + d0];
            *(uint4*)&Qo[hstr + ((((size_t)(sgrp0 + sgl) * 4 + ks) * 64 + ln) * 8)] = v;
        }
        __syncthreads();
    }
}

// ---------------------------------------------------------------------------
// Kernel 2: [ktmp|w] = x @ [wk|wproj] via bf16 MFMA, split-K 16.
// grid (16,3,16) = 768 blocks = exactly 3.0 blocks/CU (was 336 = 1.31/CU,
// i.e. ~2x imbalance: 80 CUs ran a second round while 176 idled).
// Double-buffered LDS, qgemm rhythm (reads + early stage -> s_barrier ->
// MFMA), full drain only at step end.
// ---------------------------------------------------------------------------
__global__ __launch_bounds__(256) void kw_mfma_kernel(
    const ushort* __restrict__ Xbf,   // bf16 [S][D]
    const ushort* __restrict__ WT2,   // bf16 [192][D]
    float* __restrict__ partial)      // [kc][S][192]
{
    __shared__ ushort As[2 * 128 * 64];   // 32 KB
    __shared__ ushort Bs[2 * 64 * 64];    // 16 KB

    const int tid = threadIdx.x;
    const int lane = tid & 63;
    const int wave = tid >> 6;
    const int m = lane & 15;
    const int q = lane >> 4;
    const int wm = wave & 1, wn = wave >> 1;
    const int m0 = blockIdx.x * 128;
    const int n0 = blockIdx.y * 64;
    const int kc = blockIdx.z;
    const size_t kbase = (size_t)kc * KCHUNK_SZ;

    const ushort* agp[4];
    unsigned int abase[4];
#pragma unroll
    for (int u = 0; u < 4; u++) {
        int s = (u * 4 + wave) * 64 + lane;
        int row = s >> 3, c = s & 7;
        int kg = c ^ (row & 7);
        agp[u] = Xbf + (size_t)(m0 + row) * D_DIM + kbase + kg * 8;
        abase[u] = (unsigned int)((u * 4 + wave) * 64 * 8);
    }
    const ushort* bgp[2];
    unsigned int bbase[2];
#pragma unroll
    for (int u = 0; u < 2; u++) {
        int s = (u * 4 + wave) * 64 + lane;
        int row = s >> 3, c = s & 7;
        int kg = c ^ (row & 7);
        bgp[u] = WT2 + (size_t)(n0 + row) * D_DIM + kbase + kg * 8;
        bbase[u] = (unsigned int)((u * 4 + wave) * 64 * 8);
    }

    auto stage = [&](int t) {
        ushort* da = &As[(t & 1) * 8192];
        ushort* db = &Bs[(t & 1) * 4096];
#pragma unroll
        for (int u = 0; u < 4; u++) gld_lds16(agp[u] + t * 64, da + abase[u]);
#pragma unroll
        for (int u = 0; u < 2; u++) gld_lds16(bgp[u] + t * 64, db + bbase[u]);
    };

    floatx4 acc[4][2];
#pragma unroll
    for (int i = 0; i < 4; i++)
#pragma unroll
        for (int j = 0; j < 2; j++) acc[i][j] = (floatx4){0.f, 0.f, 0.f, 0.f};

    stage(0);
    __syncthreads();

    for (int t = 0; t < KCHUNK_SZ / 64; ++t) {
        const ushort* as = &As[(t & 1) * 8192];
        const ushort* bs = &Bs[(t & 1) * 4096];

        short8 af[4], bfr[2];

        // ---- phase 1: ks0  (reads 6; stage(t+1) issued early) ----
#pragma unroll
        for (int mt = 0; mt < 4; mt++) {
            int row = wm * 64 + mt * 16 + m;
            af[mt] = *(const short8*)&as[row * 64 + ((q ^ (m & 7)) * 8)];
        }
#pragma unroll
        for (int nt = 0; nt < 2; nt++) {
            int row = wn * 32 + nt * 16 + m;
            bfr[nt] = *(const short8*)&bs[row * 64 + ((q ^ (m & 7)) * 8)];
        }
        if (t + 1 < KCHUNK_SZ / 64) stage(t + 1);
        __builtin_amdgcn_s_barrier();
        __builtin_amdgcn_s_setprio(1);
#pragma unroll
        for (int mt = 0; mt < 4; mt++)
#pragma unroll
            for (int nt = 0; nt < 2; nt++)
                acc[mt][nt] = __builtin_amdgcn_mfma_f32_16x16x32_bf16(
                    af[mt], bfr[nt], acc[mt][nt], 0, 0, 0);
        __builtin_amdgcn_s_setprio(0);
        __builtin_amdgcn_s_barrier();

        // ---- phase 2: ks1  (reads 6) ----
#pragma unroll
        for (int mt = 0; mt < 4; mt++) {
            int row = wm * 64 + mt * 16 + m;
            af[mt] = *(const short8*)&as[row * 64 + (((4 + q) ^ (m & 7)) * 8)];
        }
#pragma unroll
        for (int nt = 0; nt < 2; nt++) {
            int row = wn * 32 + nt * 16 + m;
            bfr[nt] = *(const short8*)&bs[row * 64 + (((4 + q) ^ (m & 7)) * 8)];
        }
        __builtin_amdgcn_s_barrier();
        __builtin_amdgcn_s_setprio(1);
#pragma unroll
        for (int mt = 0; mt < 4; mt++)
#pragma unroll
            for (int nt = 0; nt < 2; nt++)
                acc[mt][nt] = __builtin_amdgcn_mfma_f32_16x16x32_bf16(
                    af[mt], bfr[nt], acc[mt][nt], 0, 0, 0);
        __builtin_amdgcn_s_setprio(0);
        __syncthreads();   // drains vmcnt (stage t+1 landed) + lgkm; fences reuse
    }

#pragma unroll
    for (int mt = 0; mt < 4; mt++) {
        int grow = m0 + wm * 64 + mt * 16 + q * 4;
#pragma unroll
        for (int nt = 0; nt < 2; nt++) {
            int gn = n0 + wn * 32 + nt * 16 + m;
#pragma unroll
            for (int r = 0; r < 4; r++)
                partial[((size_t)kc * S_LEN + grow + r) * 192 + gn] = acc[mt][nt][r];
        }
    }
}

// ---------------------------------------------------------------------------
// Kernel 3: fused split-K reduce + layernorm + RoPE.  One block per s-row,
// 192 threads (3 waves): t<128 -> K path (LN+rope -> Kbf), t>=128 -> W path.
// ---------------------------------------------------------------------------
__global__ __launch_bounds__(192) void kw_reduce_norm_kernel(
    const float* __restrict__ partial,
    const float* __restrict__ gw, const float* __restrict__ gb,
    const float* __restrict__ cosp, const float* __restrict__ sinp,
    ushort* __restrict__ Kbf, float* __restrict__ Wo)
{
    __shared__ float red[128];
    __shared__ float sh[128];
    const int m = blockIdx.x, t = threadIdx.x;

    float s = 0.f;
#pragma unroll
    for (int c = 0; c < KCHUNKS; c++)
        s += partial[((size_t)c * S_LEN + m) * 192 + t];

    if (t >= HD_DIM)
        Wo[(size_t)m * H_NUM + (t - HD_DIM)] = s * W_SCALE;

    if (t < HD_DIM) red[t] = s;
    __syncthreads();
    for (int off = 64; off > 0; off >>= 1) {
        if (t < off) red[t] += red[t + off];
        __syncthreads();
    }
    float mu = red[0] * (1.f / HD_DIM);
    __syncthreads();
    float dv = s - mu;
    if (t < HD_DIM) red[t] = dv * dv;
    __syncthreads();
    for (int off = 64; off > 0; off >>= 1) {
        if (t < off) red[t] += red[t + off];
        __syncthreads();
    }
    float var = red[0] * (1.f / HD_DIM);
    float rs = rsqrtf(var + LN_EPS);
    float kn = 0.f;
    if (t < HD_DIM) { kn = dv * rs * gw[t] + gb[t]; sh[t] = kn; }
    __syncthreads();
    if (t < HD_DIM) {
        float out;
        if (t < ROPE_DIM) {
            int jj = t >> 1;
            float c = cosp[m * HALF_DIM + jj], sn = sinp[m * HALF_DIM + jj];
            out = ((t & 1) == 0) ? (sh[t] * c - sh[t + 1] * sn)
                                 : (sh[t - 1] * sn + sh[t] * c);
        } else {
            out = kn;
        }
        Kbf[(size_t)m * HD_DIM + t] = f2bf(out);
    }
}

// ---------------------------------------------------------------------------
// Kernel 4: index_score via bf16 MFMA, barrier-free head loop.
// (setprio removed: only measured precedent in multi-wave MFMA regime is
// negative, m190; R8's combined changes were net-neutral so it is the one
// suspect with adverse evidence.)
// ---------------------------------------------------------------------------
__global__ __launch_bounds__(256, 2) void attn_mfma_kernel(
    const ushort* __restrict__ Qb,  // bf16 frag layout [h][sgrp][ks][lane]x8
    const ushort* __restrict__ Kb,  // bf16 [S][HD]
    const float* __restrict__ Wf,   // fp32 [S][H], pre-scaled
    float* __restrict__ SC)
{
    __shared__ float Wsm[64 * 68];

    const int bidx = blockIdx.x;
    const int x = bidx & 7, j = bidx >> 3;
    const int g1 = x + 1, g2 = 32 - x, g3 = x + 9;   // group sizes (g4=24-x)
    int ts, tt;
    if (j < g1)                { ts = x;      tt = j; }
    else if (j < g1 + g2)      { ts = 31 - x; tt = j - g1; }
    else if (j < g1 + g2 + g3) { ts = x + 8;  tt = j - g1 - g2; }
    else                       { ts = 23 - x; tt = j - g1 - g2 - g3; }
    const int s0 = ts * 64, t0 = tt * 64;

    const int tid = threadIdx.x;
    const int lane = tid & 63;
    const int m = lane & 15;
    const int q = lane >> 4;
    const int strip = (tid >> 6) * 16;

    {
        const float4* gw = (const float4*)(Wf + (size_t)s0 * H_NUM);
#pragma unroll
        for (int u = 0; u < 4; u++) {
            int ch = tid + u * 256;
            float4 v = gw[ch];
            *(float4*)&Wsm[(ch >> 4) * 68 + (ch & 15) * 4] = v;
        }
    }

    short8 bf[4][4];   // [t-tile][k-step] — resident all block
#pragma unroll
    for (int tile = 0; tile < 4; tile++)
#pragma unroll
        for (int ks = 0; ks < 4; ks++)
            bf[tile][ks] = *(const short8*)
                &Kb[(size_t)(t0 + tile * 16 + m) * HD_DIM + ks * 32 + q * 8];

    __syncthreads();   // Wsm ready (only barrier)

    float acc[4][4];
#pragma unroll
    for (int tile = 0; tile < 4; tile++)
#pragma unroll
        for (int r = 0; r < 4; r++) acc[tile][r] = 0.f;

    const int sgrp = ts * 4 + (strip >> 4);
    const ushort* qfb = Qb + ((size_t)sgrp * 4 * 64 + lane) * 8;
    const float* wrow = &Wsm[(strip + q * 4) * 68];

    auto loadQ = [&](short8* dst, int h) {
        const ushort* p = qfb + (size_t)h * QF_HSTRIDE;
#pragma unroll
        for (int ks = 0; ks < 4; ks++) dst[ks] = *(const short8*)&p[ks * 512];
    };
    auto computeH = [&](const short8* af, int h) {
        float wv[4];
#pragma unroll
        for (int r = 0; r < 4; r++) wv[r] = wrow[r * 68 + h];
#pragma unroll
        for (int tile = 0; tile < 4; tile++) {
            floatx4 p = {0.f, 0.f, 0.f, 0.f};
#pragma unroll
            for (int ks = 0; ks < 4; ks++)
                p = __builtin_amdgcn_mfma_f32_16x16x32_bf16(af[ks], bf[tile][ks], p, 0, 0, 0);
#pragma unroll
            for (int r = 0; r < 4; r++)
                acc[tile][r] += fmaxf(p[r], 0.f) * wv[r];
        }
    };

    short8 afA[4], afB[4];
    loadQ(afA, 0);
    for (int h = 0; h < H_NUM; h += 2) {
        loadQ(afB, h + 1);
        computeH(afA, h);
        if (h + 2 < H_NUM) loadQ(afA, h + 2);
        computeH(afB, h + 1);
    }

#pragma unroll
    for (int tile = 0; tile < 4; tile++)
#pragma unroll
        for (int r = 0; r < 4; r++)
            SC[(size_t)(s0 + strip + q * 4 + r) * S_LEN + t0 + tile * 16 + m] =
                acc[tile][r];
}

// ---------------------------------------------------------------------------
// Kernel 5: per-row top-512, u32 compressed keys, causal-length-adaptive
// partial bitonic.  512 threads: halves the serial iterations per sort step.
// ---------------------------------------------------------------------------
__device__ __forceinline__ unsigned int fkey(float f) {
    unsigned int u = __float_as_uint(f);
    return (u & 0x80000000u) ? ~u : (u | 0x80000000u);
}

__global__ __launch_bounds__(512) void topk_kernel(
    const float* __restrict__ SC, float* __restrict__ outv, float* __restrict__ outi)
{
    __shared__ unsigned int key[S_LEN];
    __shared__ float val[S_LEN];
    const int s = blockIdx.x, tid = threadIdx.x;
    const int nchunks = (s >> 9) + 1;          // 1..4 active 512-chunks
    const int nact = nchunks << 9;

    for (int t = tid; t < nact; t += 512) {
        float v = (t <= s) ? SC[(size_t)s * S_LEN + t] : NEG_INF_F;
        val[t] = v;
        key[t] = (fkey(v) & 0xFFFFF800u) | (unsigned int)(S_LEN - 1 - t);
    }
    __syncthreads();

    // Phase 1: sort each active 512-chunk descending (local-index network)
    for (int k2 = 2; k2 <= 512; k2 <<= 1) {
        for (int j = k2 >> 1; j > 0; j >>= 1) {
            for (int p = tid; p < (nact >> 1); p += 512) {
                int i = 2 * p - (p & (j - 1));
                int il = i & 511;
                unsigned int a = key[i], b = key[i + j];
                bool up = ((il & k2) == 0);
                bool sw = up ? (a < b) : (a > b);
                if (sw) { key[i] = b; key[i + j] = a; }
            }
            __syncthreads();
        }
    }

    // Phase 2: fold chunks c=1.. into chunk 0 (top-512 of union each time)
    for (int c = 1; c < nchunks; c++) {
        {
            int p = tid;                          // 512 threads, 512 slots
            unsigned int a = key[p], b = key[(c << 9) + 511 - p];
            key[p] = a > b ? a : b;               // bitonic, contains top-512
        }
        __syncthreads();
        for (int j = 256; j > 0; j >>= 1) {       // bitonic merge, descending
            if (tid < 256) {
                int i = 2 * tid - (tid & (j - 1));
                unsigned int a = key[i], b = key[i + j];
                if (a < b) { key[i] = b; key[i + j] = a; }
            }
            __syncthreads();
        }
    }

    for (int i2 = tid; i2 < TOPK_N; i2 += 512) {
        unsigned int kv = key[i2];
        int t = S_LEN - 1 - (int)(kv & 0x7FFu);
        outv[(size_t)s * TOPK_N + i2] = val[t];
        outi[(size_t)s * TOPK_N + i2] = (float)t;
    }
}

// ---------------------------------------------------------------------------
extern "C" void kernel_launch(void* const* d_in, const int* in_sizes, int n_in,
                              void* d_out, int out_size, void* d_ws, size_t ws_size,
                              hipStream_t stream)
{
    (void)in_sizes; (void)n_in; (void)out_size; (void)ws_size;
    const float* x      = (const float*)d_in[0];
    const float* q_lora = (const float*)d_in[1];
    const float* wq_b   = (const float*)d_in[2];
    const float* wk     = (const float*)d_in[3];
    const float* wproj  = (const float*)d_in[4];
    const float* knw    = (const float*)d_in[5];
    const float* knb    = (const float*)d_in[6];
    const float* cosp   = (const float*)d_in[7];
    const float* sinp   = (const float*)d_in[8];

    float* ws = (float*)d_ws;
    ushort* Qbf  = (ushort*)(ws + QBF_OFF);
    ushort* Albf = (ushort*)(ws + ALORA_OFF);
    ushort* WTbf = (ushort*)(ws + WT_OFF);
    ushort* Xbf  = (ushort*)(ws + XBF_OFF);
    ushort* WT2  = (ushort*)(ws + WT2_OFF);
    ushort* Kbf  = (ushort*)(ws + KBF_OFF);
    float*  Wf   = ws + WF_OFF;
    float*  SCb  = ws + SC_OFF;
    float*  partial = ws + QBF_OFF;  // alias QBF: produced by kernel 2,
                                     // consumed by kernel 3; Qbf first
                                     // written by kernel 4 (16*S*192 = 6.29M
                                     // floats <= 8.39M region)

    float* outv = (float*)d_out;
    float* outi = outv + (size_t)S_LEN * TOPK_N;

    prep_kernel<<<PREP_TOTAL, 256, 0, stream>>>(
        q_lora, Albf, x, Xbf, wq_b, WTbf, wk, wproj, WT2);
    kw_mfma_kernel<<<dim3(S_LEN / 128, 3, KCHUNKS), 256, 0, stream>>>(Xbf, WT2, partial);
    kw_reduce_norm_kernel<<<S_LEN, 192, 0, stream>>>(
        partial, knw, knb, cosp, sinp, Kbf, Wf);
    qgemm_mfma_kernel<<<256, 512, 0, stream>>>(Albf, WTbf, cosp, sinp, Qbf);
    attn_mfma_kernel<<<528, 256, 0, stream>>>(Qbf, Kbf, Wf, SCb);
    topk_kernel<<<S_LEN, 512, 0, stream>>>(SCb, outv, outi);
}